// Round 2
// baseline (86.065 us; speedup 1.0000x reference)
//
#include <hip/hip_runtime.h>

// HardTripletMiningLoss: 480 embeddings (anchor|positive|negative), D=128.
// td[i,j,k] = pd[i,j] - pd[j,k] + A, keep = same[i,j] & !same[j,k], keep[0]=F.
// j is the anchor; pd symmetric => per anchor row a:
//   positives i: label[i]==label[a] && i != 0   (includes i==a, pd=0)
//   negatives k: label[k]!=label[a]
//   accumulate relu(pd[a,i] + A - pd[a,k]); loss = sum/count.
// Single fused kernel: per-block partial + last-block-done final reduce.

#define NROWS 480
#define DDIM  128
#define BLK   256
#define MARGIN 0.2f

__device__ __forceinline__ const float* emb_row(const float* a, const float* p,
                                                const float* n, int r) {
  if (r < 160) return a + r * DDIM;
  if (r < 320) return p + (r - 160) * DDIM;
  return n + (r - 320) * DDIM;
}

__global__ __launch_bounds__(BLK) void triplet_fused(
    const float* __restrict__ anch, const float* __restrict__ posi,
    const float* __restrict__ nega, const int* __restrict__ ind,
    float* __restrict__ partials, unsigned* __restrict__ counter,
    float* __restrict__ out) {
  __shared__ float ei[DDIM];
  __shared__ float pdrow[NROWS];
  __shared__ int   labels[NROWS];
  __shared__ int   poslist[NROWS];
  __shared__ int   npos;
  __shared__ int   is_last;
  __shared__ float red_s[BLK / 64], red_c[BLK / 64];
  __shared__ double dred_s[BLK / 64], dred_c[BLK / 64];

  const int tid = threadIdx.x;
  const int a = blockIdx.x;  // anchor row (j in reference notation)

  for (int t = tid; t < NROWS; t += BLK) labels[t] = ind[t];
  if (tid == 0) { npos = 0; is_last = 0; }
  {
    const float* ra = emb_row(anch, posi, nega, a);
    if (tid < DDIM) ei[tid] = ra[tid];
  }
  __syncthreads();

  const int la = labels[a];
  for (int r = tid; r < NROWS; r += BLK) {
    const float4* er = (const float4*)emb_row(anch, posi, nega, r);
    float d2 = 0.f;
#pragma unroll
    for (int dd = 0; dd < DDIM / 4; ++dd) {
      float4 b = er[dd];
      float x0 = ei[4 * dd + 0] - b.x;
      float x1 = ei[4 * dd + 1] - b.y;
      float x2 = ei[4 * dd + 2] - b.z;
      float x3 = ei[4 * dd + 3] - b.w;
      d2 += x0 * x0 + x1 * x1 + x2 * x2 + x3 * x3;
    }
    pdrow[r] = d2;  // exact ||e_a - e_r||^2, symmetric, >= 0
    if (labels[r] == la && r != 0) {  // positive list; i==0 slice excluded
      int slot = atomicAdd(&npos, 1);
      poslist[slot] = r;
    }
  }
  __syncthreads();

  float s = 0.f, c = 0.f;
  {
    const int k0 = tid, k1 = tid + BLK;  // each thread owns 2 candidate k's
    const float pk0 = pdrow[k0];
    const bool g0 = (labels[k0] != la);
    float pk1 = 0.f;
    bool g1 = false;
    if (k1 < NROWS) { pk1 = pdrow[k1]; g1 = (labels[k1] != la); }
    const int np = npos;
    for (int ii = 0; ii < np; ++ii) {
      const float tb = pdrow[poslist[ii]] + MARGIN;
      float td0 = tb - pk0;
      if (g0 && td0 > 0.f) { s += td0; c += 1.f; }
      float td1 = tb - pk1;
      if (g1 && td1 > 0.f) { s += td1; c += 1.f; }
    }
  }

  // block reduction: wave64 shuffle then cross-wave via LDS
  for (int off = 32; off > 0; off >>= 1) {
    s += __shfl_down(s, off, 64);
    c += __shfl_down(c, off, 64);
  }
  const int wave = tid >> 6, lane = tid & 63;
  if (lane == 0) { red_s[wave] = s; red_c[wave] = c; }
  __syncthreads();
  if (tid == 0) {
    float ts = 0.f, tc = 0.f;
    for (int w = 0; w < BLK / 64; ++w) { ts += red_s[w]; tc += red_c[w]; }
    partials[2 * a] = ts;
    partials[2 * a + 1] = tc;
    __threadfence();  // partials visible device-wide before counter bump
    unsigned old = atomicAdd(counter, 1u);  // device scope by default
    if (old == (unsigned)(gridDim.x - 1)) is_last = 1;
  }
  __syncthreads();

  if (is_last) {
    __threadfence();  // acquire: see all blocks' partials
    double ds = 0.0, dc = 0.0;
    for (int b = tid; b < NROWS; b += BLK) {
      ds += (double)partials[2 * b];
      dc += (double)partials[2 * b + 1];
    }
    for (int off = 32; off > 0; off >>= 1) {
      ds += __shfl_down(ds, off, 64);
      dc += __shfl_down(dc, off, 64);
    }
    if (lane == 0) { dred_s[wave] = ds; dred_c[wave] = dc; }
    __syncthreads();
    if (tid == 0) {
      double ts = 0.0, tc = 0.0;
      for (int w = 0; w < BLK / 64; ++w) { ts += dred_s[w]; tc += dred_c[w]; }
      out[0] = (tc > 0.0) ? (float)(ts / tc) : 0.0f;
    }
  }
}

extern "C" void kernel_launch(void* const* d_in, const int* in_sizes, int n_in,
                              void* d_out, int out_size, void* d_ws, size_t ws_size,
                              hipStream_t stream) {
  const float* anch = (const float*)d_in[0];
  const float* posi = (const float*)d_in[1];
  const float* nega = (const float*)d_in[2];
  const int*   ind  = (const int*)d_in[3];
  float* out = (float*)d_out;
  float* partials = (float*)d_ws;                       // 960 floats
  unsigned* counter = (unsigned*)((char*)d_ws + 4096);  // 4B, zeroed below

  hipMemsetAsync(counter, 0, sizeof(unsigned), stream);  // graph-capturable
  triplet_fused<<<NROWS, BLK, 0, stream>>>(anch, posi, nega, ind,
                                           partials, counter, out);
}